// Round 2
// baseline (180.473 us; speedup 1.0000x reference)
//
#include <hip/hip_runtime.h>

// BlockResMLP mixer, fused. Transposed-GEMM formulation:
//   hT = W1T @ xT   (MFMA C-layout of hT chunks == B-operand layout of GEMM2
//                    under a chosen hidden-dim permutation baked into the W2 pack)
//   yT = E_c2 @ xT (residual) + W2T @ hT (+ b2)
// so the hidden activation never touches LDS. Inter-layer 32x32 transpose goes
// through one LDS tile with a per-block-row rotation swizzle; layer-2's W1 pack
// uses k-order kz=4j+q so the gather is paired-dword, ~2-way banks (free).

typedef unsigned short u16t;
typedef __bf16 bf16x8 __attribute__((ext_vector_type(8)));
typedef float f32x4 __attribute__((ext_vector_type(4)));

#define LDC 34   // u16 per tile row: 32 cols + 2 pad (17 dwords -> odd dword stride)

__device__ __forceinline__ u16t f2b(float f) {           // fp32 -> bf16 RNE
  union { float f; unsigned u; } v; v.f = f;
  unsigned r = v.u + 0x7FFFu + ((v.u >> 16) & 1u);
  return (u16t)(r >> 16);
}
__device__ __forceinline__ float b2f(u16t h) {
  union { unsigned u; float f; } v; v.u = ((unsigned)h) << 16;
  return v.f;
}

union BF { u16t us[8]; bf16x8 v; };

// ---------------- weight pack: fp32 -> bf16 MFMA A-fragment order (transposed GEMMs) ----
// pW1[L][n][c][lane][j]  = W1[n][kz][c*16+t]    kz = L==0 ? q*8+j : 4*j+q
// pW2[L][n][kc*2+c2][lane][j] = W2[n][H][c2*16+t],  H = kc*32+(j>>2)*16+q*4+(j&3)
__global__ __launch_bounds__(256) void pack_weights(
    const float* __restrict__ W1a, const float* __restrict__ W2a,
    const float* __restrict__ W1b, const float* __restrict__ W2b,
    u16t* __restrict__ pW1, u16t* __restrict__ pW2) {
  int tidg = blockIdx.x * 256 + threadIdx.x;   // 0..32767
  int tensor = tidg >> 14;
  int r  = tidg & 16383;
  int L  = r >> 13;
  int r2 = r & 8191;
  int n    = r2 >> 8;
  int f    = (r2 >> 6) & 3;
  int lane = r2 & 63;
  int q = lane >> 4, t = lane & 15;

  union { u16t us[8]; uint4 v; } w;
  if (tensor == 0) {
    const float* src = L ? W1b : W1a;
#pragma unroll
    for (int j = 0; j < 8; j++) {
      int kz = L ? (4 * j + q) : (q * 8 + j);
      w.us[j] = f2b(src[n * 2048 + kz * 64 + f * 16 + t]);
    }
    *(uint4*)(pW1 + (size_t)((L * 32 + n) * 2048 + f * 512 + lane * 8)) = w.v;
  } else {
    const float* src = L ? W2b : W2a;
    int kc = f >> 1, c2 = f & 1;
#pragma unroll
    for (int j = 0; j < 8; j++) {
      int H = kc * 32 + (j >> 2) * 16 + q * 4 + (j & 3);
      w.us[j] = f2b(src[n * 2048 + H * 32 + c2 * 16 + t]);
    }
    *(uint4*)(pW2 + (size_t)((L * 32 + n) * 2048 + f * 512 + lane * 8)) = w.v;
  }
}

// ---------------- per-layer compute: 8 blocks per wave, all-register hidden ----------------
template <int L>
__device__ __forceinline__ void compute_layer(
    const bf16x8* afr, unsigned* __restrict__ tile32,
    const u16t* __restrict__ pW1, const u16t* __restrict__ pW2,
    const float* __restrict__ b1, const float* __restrict__ b2,
    const bf16x8* E, int w, int q, int t, int lane) {
  const f32x4 zf = {0.f, 0.f, 0.f, 0.f};
#pragma unroll
  for (int u = 0; u < 8; u++) {
    const int n = w * 8 + u;
    const int base = (L * 32 + n) * 2048 + lane * 8;
    bf16x8 w1f[4], w2f[4];
#pragma unroll
    for (int c = 0; c < 4; c++) {
      w1f[c] = *(const bf16x8*)(pW1 + base + c * 512);
      w2f[c] = *(const bf16x8*)(pW2 + base + c * 512);
    }
    // hT chunks: lane(q,t) reg r = h_pre[c*16+q*4+r][batch t]
    f32x4 accH[4];
#pragma unroll
    for (int c = 0; c < 4; c++)
      accH[c] = __builtin_amdgcn_mfma_f32_16x16x32_bf16(w1f[c], afr[u], zf, 0, 0, 0);

    // bias + ELU + bf16; in-lane re-label to GEMM2 B-frags (kc=0: chunks 0,1; kc=1: 2,3)
    BF hf[2];
#pragma unroll
    for (int c = 0; c < 4; c++) {
      union { float4 v; float f[4]; } B1;
      B1.v = *(const float4*)(b1 + n * 64 + c * 16 + q * 4);
#pragma unroll
      for (int r = 0; r < 4; r++) {
        float vv = accH[c][r] + B1.f[r];
        vv = vv > 0.f ? vv : (__expf(vv) - 1.f);
        hf[c >> 1].us[(c & 1) * 4 + r] = f2b(vv);
      }
    }

    // yT chunks = residual(selector-MFMA) + hT@W2-frags, + b2, -> LDS tile (rotated)
#pragma unroll
    for (int c2 = 0; c2 < 2; c2++) {
      f32x4 acc = __builtin_amdgcn_mfma_f32_16x16x32_bf16(E[c2], afr[u], zf, 0, 0, 0);
      acc = __builtin_amdgcn_mfma_f32_16x16x32_bf16(w2f[c2],     hf[0].v, acc, 0, 0, 0);
      acc = __builtin_amdgcn_mfma_f32_16x16x32_bf16(w2f[2 + c2], hf[1].v, acc, 0, 0, 0);
      union { float4 v; float f[4]; } B2;
      B2.v = *(const float4*)(b2 + n * 32 + c2 * 16 + q * 4);
      const int phys = ((c2 * 16 + q * 4) + 4 * (n >> 2)) & 31;    // rotation by block row
      const int a32 = (((n * 16 + t) * LDC) + phys) >> 1;          // even u16 -> dword idx
      unsigned d0 = (unsigned)f2b(acc[0] + B2.f[0]) | ((unsigned)f2b(acc[1] + B2.f[1]) << 16);
      unsigned d1 = (unsigned)f2b(acc[2] + B2.f[2]) | ((unsigned)f2b(acc[3] + B2.f[3]) << 16);
      tile32[a32] = d0;
      tile32[a32 + 1] = d1;
    }
  }
}

__global__ __launch_bounds__(256, 4) void mixer_kernel(
    const float* __restrict__ x,
    const float* __restrict__ b1a, const float* __restrict__ b2a,
    const float* __restrict__ b1b, const float* __restrict__ b2b,
    const u16t* __restrict__ pW1, const u16t* __restrict__ pW2,
    float* __restrict__ out) {
  __shared__ unsigned tile32[(32 * 16 * LDC) / 2];   // 34,816 B -> 4 WG/CU
  const u16t* tile16 = (const u16t*)tile32;
  const int tid = threadIdx.x, w = tid >> 6, lane = tid & 63;
  const int q = lane >> 4, t = lane & 15;
  const int r0 = blockIdx.x * 16;

  // layer-1 B-frags straight from global: xT as B[k=q*8+j][n=t]
  bf16x8 afr[8];
#pragma unroll
  for (int u = 0; u < 8; u++) {
    const int n = w * 8 + u;
    const float* gp = x + (size_t)(r0 + t) * 1024 + n * 32 + q * 8;
    float4 v0 = *(const float4*)gp;
    float4 v1 = *(const float4*)(gp + 4);
    BF a;
    a.us[0] = f2b(v0.x); a.us[1] = f2b(v0.y); a.us[2] = f2b(v0.z); a.us[3] = f2b(v0.w);
    a.us[4] = f2b(v1.x); a.us[5] = f2b(v1.y); a.us[6] = f2b(v1.z); a.us[7] = f2b(v1.w);
    afr[u] = a.v;
  }

  // residual selector A-frags, layer 1 (k-order q*8+j)
  bf16x8 E[2];
#pragma unroll
  for (int c2 = 0; c2 < 2; c2++) {
    BF e;
#pragma unroll
    for (int j = 0; j < 8; j++)
      e.us[j] = (q * 8 + j == c2 * 16 + t) ? (u16t)0x3F80 : (u16t)0;
    E[c2] = e.v;
  }

  compute_layer<0>(afr, tile32, pW1, pW2, b1a, b2a, E, w, q, t, lane);
  __syncthreads();

  // transition: z[t][kz=4j+q] = y1[t][kz*32+n2]; paired-dword gathers, 2-way banks
  BF zfr[8];
#pragma unroll
  for (int j = 0; j < 8; j++) {
    const int k = 4 * j + q;
    const int rb = (k * 16 + t) * LDC;
#pragma unroll
    for (int g = 0; g < 2; g++) {
      const int pg = (8 * w + 4 * g + 4 * j) & 31;   // rotated granule for block-row k
      const unsigned d0 = tile32[(rb + pg) >> 1];
      const unsigned d1 = tile32[((rb + pg) >> 1) + 1];
      zfr[4 * g + 0].us[j] = (u16t)(d0 & 0xFFFF);
      zfr[4 * g + 1].us[j] = (u16t)(d0 >> 16);
      zfr[4 * g + 2].us[j] = (u16t)(d1 & 0xFFFF);
      zfr[4 * g + 3].us[j] = (u16t)(d1 >> 16);
    }
  }

  // residual selector A-frags, layer 2 (k-order 4j+q)
#pragma unroll
  for (int c2 = 0; c2 < 2; c2++) {
    BF e;
#pragma unroll
    for (int j = 0; j < 8; j++)
      e.us[j] = (4 * j + q == c2 * 16 + t) ? (u16t)0x3F80 : (u16t)0;
    E[c2] = e.v;
  }
  __syncthreads();   // all gathers done before tile is overwritten

  compute_layer<1>((const bf16x8*)zfr, tile32, pW1, pW2, b1b, b2b, E, w, q, t, lane);
  __syncthreads();

  // output: tile[n2][row][phys(cc)] -> out[row][F=cc*32+n2], coalesced float4 stores
  const int row = lane & 15, l4 = lane >> 4;
#pragma unroll
  for (int i = 0; i < 16; i++) {
    const int F0 = 4 * (i * 16 + w * 4 + l4);
    const int bn = F0 & 31, cc = F0 >> 5;
    const int phys = (cc + 4 * (bn >> 2)) & 31;
    union { float4 v; float f[4]; } o;
#pragma unroll
    for (int e = 0; e < 4; e++)
      o.f[e] = b2f(tile16[((bn + e) * 16 + row) * LDC + phys]);
    *(float4*)(out + (size_t)(r0 + row) * 1024 + F0) = o.v;
  }
}

extern "C" void kernel_launch(void* const* d_in, const int* in_sizes, int n_in,
                              void* d_out, int out_size, void* d_ws, size_t ws_size,
                              hipStream_t stream) {
  const float* x   = (const float*)d_in[0];
  const float* W1a = (const float*)d_in[1];
  const float* b1a = (const float*)d_in[2];
  const float* W2a = (const float*)d_in[3];
  const float* b2a = (const float*)d_in[4];
  const float* W1b = (const float*)d_in[5];
  const float* b1b = (const float*)d_in[6];
  const float* W2b = (const float*)d_in[7];
  const float* b2b = (const float*)d_in[8];
  float* out = (float*)d_out;

  u16t* pW1 = (u16t*)d_ws;
  u16t* pW2 = pW1 + 131072;   // 256 KB each, 512 KB total in d_ws

  const int rows = in_sizes[0] / 1024;

  pack_weights<<<128, 256, 0, stream>>>(W1a, W2a, W1b, W2b, pW1, pW2);
  mixer_kernel<<<rows / 16, 256, 0, stream>>>(x, b1a, b2a, b1b, b2b, pW1, pW2, out);
}

// Round 3
// 175.033 us; speedup vs baseline: 1.0311x; 1.0311x over previous
//
#include <hip/hip_runtime.h>

// BlockResMLP mixer, fused. Transposed-GEMM formulation:
//   hT = W1T @ xT   (MFMA C-layout of hT chunks == B-operand layout of GEMM2
//                    under a hidden-dim permutation baked into the W2 pack)
//   yT = E_c2 @ xT (residual, bias in C) + W2T @ hT
// Hidden activation never touches LDS. Inter-layer 32x32 transpose via one LDS
// tile with per-block-row rotation; layer-2 W1 pack uses k-order kz=4j+q so the
// gather is paired-dword. R3: no launch_bounds VGPR cap (R2's 64-reg cap caused
// ~36MB scratch spill traffic), x streamed per-block, bias folded into MFMA C,
// packed bf16 converts.

typedef unsigned short u16t;
typedef __bf16 bf16x8 __attribute__((ext_vector_type(8)));
typedef __bf16 bf16x2 __attribute__((ext_vector_type(2)));
typedef float f32x4 __attribute__((ext_vector_type(4)));

#define LDC 34   // u16 per tile row: 32 cols + 2 pad (17 dwords -> odd dword stride)

__device__ __forceinline__ u16t f2b(float f) {           // fp32 -> bf16 RNE
  union { float f; unsigned u; } v; v.f = f;
  unsigned r = v.u + 0x7FFFu + ((v.u >> 16) & 1u);
  return (u16t)(r >> 16);
}
__device__ __forceinline__ float b2f(u16t h) {
  union { unsigned u; float f; } v; v.u = ((unsigned)h) << 16;
  return v.f;
}
__device__ __forceinline__ unsigned pk2(float a, float b) {  // 2x fp32 -> packed bf16
#if __has_builtin(__builtin_amdgcn_cvt_pk_bf16_f32)
  union { bf16x2 v; unsigned u; } cv;
  cv.v = __builtin_amdgcn_cvt_pk_bf16_f32(a, b);
  return cv.u;
#else
  return (unsigned)f2b(a) | ((unsigned)f2b(b) << 16);
#endif
}

union BF { u16t us[8]; unsigned d[4]; bf16x8 v; };

// ---------------- weight pack: fp32 -> bf16 MFMA A-fragment order (transposed GEMMs) ----
// pW1[L][n][c][lane][j]  = W1[n][kz][c*16+t]    kz = L==0 ? q*8+j : 4*j+q
// pW2[L][n][kc*2+c2][lane][j] = W2[n][H][c2*16+t],  H = kc*32+(j>>2)*16+q*4+(j&3)
__global__ __launch_bounds__(256) void pack_weights(
    const float* __restrict__ W1a, const float* __restrict__ W2a,
    const float* __restrict__ W1b, const float* __restrict__ W2b,
    u16t* __restrict__ pW1, u16t* __restrict__ pW2) {
  int tidg = blockIdx.x * 256 + threadIdx.x;   // 0..32767
  int tensor = tidg >> 14;
  int r  = tidg & 16383;
  int L  = r >> 13;
  int r2 = r & 8191;
  int n    = r2 >> 8;
  int f    = (r2 >> 6) & 3;
  int lane = r2 & 63;
  int q = lane >> 4, t = lane & 15;

  union { u16t us[8]; uint4 v; } w;
  if (tensor == 0) {
    const float* src = L ? W1b : W1a;
#pragma unroll
    for (int j = 0; j < 8; j++) {
      int kz = L ? (4 * j + q) : (q * 8 + j);
      w.us[j] = f2b(src[n * 2048 + kz * 64 + f * 16 + t]);
    }
    *(uint4*)(pW1 + (size_t)((L * 32 + n) * 2048 + f * 512 + lane * 8)) = w.v;
  } else {
    const float* src = L ? W2b : W2a;
    int kc = f >> 1, c2 = f & 1;
#pragma unroll
    for (int j = 0; j < 8; j++) {
      int H = kc * 32 + (j >> 2) * 16 + q * 4 + (j & 3);
      w.us[j] = f2b(src[n * 2048 + H * 32 + c2 * 16 + t]);
    }
    *(uint4*)(pW2 + (size_t)((L * 32 + n) * 2048 + f * 512 + lane * 8)) = w.v;
  }
}

// ---------------- per-layer compute: 8 blocks per wave, all-register hidden ----------------
// L==0: A-frags packed on the fly from global x (xg = lane's row base).
// L==1: A-frags from pre-gathered zfr.
template <int L>
__device__ __forceinline__ void compute_layer(
    const float* __restrict__ xg, const bf16x8* zfr,
    unsigned* __restrict__ tile32,
    const u16t* __restrict__ pW1, const u16t* __restrict__ pW2,
    const float* __restrict__ b1, const float* __restrict__ b2,
    const bf16x8* E, int w, int q, int t) {
  const int lane8 = (q * 16 + t) * 8;
  float4 v0, v1;
  if (L == 0) {
    const float* gp = xg + (w * 8) * 32 + q * 8;
    v0 = *(const float4*)gp;
    v1 = *(const float4*)(gp + 4);
  }
#pragma unroll
  for (int u = 0; u < 8; u++) {
    const int n = w * 8 + u;
    bf16x8 af;
    if (L == 0) {
      BF a;
      a.d[0] = pk2(v0.x, v0.y); a.d[1] = pk2(v0.z, v0.w);
      a.d[2] = pk2(v1.x, v1.y); a.d[3] = pk2(v1.z, v1.w);
      af = a.v;
      if (u < 7) {                      // issue next block's x loads early
        const float* gp = xg + (n + 1) * 32 + q * 8;
        v0 = *(const float4*)gp;
        v1 = *(const float4*)(gp + 4);
      }
    } else {
      af = zfr[u];
    }

    const int base = (L * 32 + n) * 2048 + lane8;
    bf16x8 w1f[4], w2f[4];
#pragma unroll
    for (int c = 0; c < 4; c++) {
      w1f[c] = *(const bf16x8*)(pW1 + base + c * 512);
      w2f[c] = *(const bf16x8*)(pW2 + base + c * 512);
    }

    // hT chunks: lane(q,t) reg r = h_pre[c*16+q*4+r][batch t]; bias via C operand
    BF hf[2];
#pragma unroll
    for (int c = 0; c < 4; c++) {
      float4 B1 = *(const float4*)(b1 + n * 64 + c * 16 + q * 4);
      f32x4 bc = {B1.x, B1.y, B1.z, B1.w};
      f32x4 acc = __builtin_amdgcn_mfma_f32_16x16x32_bf16(w1f[c], af, bc, 0, 0, 0);
      float e0 = acc[0] > 0.f ? acc[0] : (__expf(acc[0]) - 1.f);
      float e1 = acc[1] > 0.f ? acc[1] : (__expf(acc[1]) - 1.f);
      float e2 = acc[2] > 0.f ? acc[2] : (__expf(acc[2]) - 1.f);
      float e3 = acc[3] > 0.f ? acc[3] : (__expf(acc[3]) - 1.f);
      hf[c >> 1].d[(c & 1) * 2 + 0] = pk2(e0, e1);
      hf[c >> 1].d[(c & 1) * 2 + 1] = pk2(e2, e3);
    }

    // yT = E@xT (+b2 in C) + W2T@hT ; bf16 -> LDS tile (rotated granules)
#pragma unroll
    for (int c2 = 0; c2 < 2; c2++) {
      float4 B2 = *(const float4*)(b2 + n * 32 + c2 * 16 + q * 4);
      f32x4 bc = {B2.x, B2.y, B2.z, B2.w};
      f32x4 acc = __builtin_amdgcn_mfma_f32_16x16x32_bf16(E[c2], af, bc, 0, 0, 0);
      acc = __builtin_amdgcn_mfma_f32_16x16x32_bf16(w2f[c2],     hf[0].v, acc, 0, 0, 0);
      acc = __builtin_amdgcn_mfma_f32_16x16x32_bf16(w2f[2 + c2], hf[1].v, acc, 0, 0, 0);
      const int phys = ((c2 * 16 + q * 4) + 4 * (n >> 2)) & 31;    // rotation by block row
      const int a32 = (((n * 16 + t) * LDC) + phys) >> 1;          // even u16 -> dword idx
      tile32[a32]     = pk2(acc[0], acc[1]);
      tile32[a32 + 1] = pk2(acc[2], acc[3]);
    }
  }
}

__global__ __launch_bounds__(256) void mixer_kernel(
    const float* __restrict__ x,
    const float* __restrict__ b1a, const float* __restrict__ b2a,
    const float* __restrict__ b1b, const float* __restrict__ b2b,
    const u16t* __restrict__ pW1, const u16t* __restrict__ pW2,
    float* __restrict__ out) {
  __shared__ unsigned tile32[(32 * 16 * LDC) / 2];   // 34,816 B -> 4 WG/CU by LDS
  const u16t* tile16 = (const u16t*)tile32;
  const int tid = threadIdx.x, w = tid >> 6, lane = tid & 63;
  const int q = lane >> 4, t = lane & 15;
  const int r0 = blockIdx.x * 16;
  const float* xg = x + (size_t)(r0 + t) * 1024;

  // residual selector A-frags, layer 1 (k-order q*8+j)
  bf16x8 E[2];
#pragma unroll
  for (int c2 = 0; c2 < 2; c2++) {
    BF e;
#pragma unroll
    for (int j = 0; j < 8; j++)
      e.us[j] = (q * 8 + j == c2 * 16 + t) ? (u16t)0x3F80 : (u16t)0;
    E[c2] = e.v;
  }

  compute_layer<0>(xg, nullptr, tile32, pW1, pW2, b1a, b2a, E, w, q, t);
  __syncthreads();

  // transition: z[t][kz=4j+q] = y1[t][kz*32+n2]; paired-dword gathers
  BF zfr[8];
#pragma unroll
  for (int j = 0; j < 8; j++) {
    const int k = 4 * j + q;
    const int rb = (k * 16 + t) * LDC;
#pragma unroll
    for (int g = 0; g < 2; g++) {
      const int pg = (8 * w + 4 * g + 4 * j) & 31;   // rotated granule for block-row k
      const unsigned d0 = tile32[(rb + pg) >> 1];
      const unsigned d1 = tile32[((rb + pg) >> 1) + 1];
      zfr[4 * g + 0].us[j] = (u16t)(d0 & 0xFFFF);
      zfr[4 * g + 1].us[j] = (u16t)(d0 >> 16);
      zfr[4 * g + 2].us[j] = (u16t)(d1 & 0xFFFF);
      zfr[4 * g + 3].us[j] = (u16t)(d1 >> 16);
    }
  }

  // residual selector A-frags, layer 2 (k-order 4j+q)
#pragma unroll
  for (int c2 = 0; c2 < 2; c2++) {
    BF e;
#pragma unroll
    for (int j = 0; j < 8; j++)
      e.us[j] = (4 * j + q == c2 * 16 + t) ? (u16t)0x3F80 : (u16t)0;
    E[c2] = e.v;
  }
  __syncthreads();   // all gathers done before tile is overwritten

  compute_layer<1>(nullptr, (const bf16x8*)zfr, tile32, pW1, pW2, b1b, b2b, E, w, q, t);
  __syncthreads();

  // output: tile[n2][row][phys(cc)] -> out[row][F=cc*32+n2], coalesced float4 stores
  const int row = lane & 15, l4 = lane >> 4;
#pragma unroll
  for (int i = 0; i < 16; i++) {
    const int F0 = 4 * (i * 16 + w * 4 + l4);
    const int bn = F0 & 31, cc = F0 >> 5;
    const int phys = (cc + 4 * (bn >> 2)) & 31;
    union { float4 v; float f[4]; } o;
#pragma unroll
    for (int e = 0; e < 4; e++)
      o.f[e] = b2f(tile16[((bn + e) * 16 + row) * LDC + phys]);
    *(float4*)(out + (size_t)(r0 + row) * 1024 + F0) = o.v;
  }
}

extern "C" void kernel_launch(void* const* d_in, const int* in_sizes, int n_in,
                              void* d_out, int out_size, void* d_ws, size_t ws_size,
                              hipStream_t stream) {
  const float* x   = (const float*)d_in[0];
  const float* W1a = (const float*)d_in[1];
  const float* b1a = (const float*)d_in[2];
  const float* W2a = (const float*)d_in[3];
  const float* b2a = (const float*)d_in[4];
  const float* W1b = (const float*)d_in[5];
  const float* b1b = (const float*)d_in[6];
  const float* W2b = (const float*)d_in[7];
  const float* b2b = (const float*)d_in[8];
  float* out = (float*)d_out;

  u16t* pW1 = (u16t*)d_ws;
  u16t* pW2 = pW1 + 131072;   // 256 KB each, 512 KB total in d_ws

  const int rows = in_sizes[0] / 1024;

  pack_weights<<<128, 256, 0, stream>>>(W1a, W2a, W1b, W2b, pW1, pW2);
  mixer_kernel<<<rows / 16, 256, 0, stream>>>(x, b1a, b2a, b1b, b2b, pW1, pW2, out);
}

// Round 4
// 165.947 us; speedup vs baseline: 1.0875x; 1.0548x over previous
//
#include <hip/hip_runtime.h>

// BlockResMLP mixer, fused. Transposed-GEMM formulation:
//   hT = W1T @ xT (+b1 in C)   -- MFMA C-layout of hT == B-operand layout of GEMM2
//                                 under a hidden-dim permutation baked into the W2 pack
//   yT = E_c2 @ xT (+b2 in C, residual) + W2T @ hT
// Hidden activation never touches LDS. R4: register double-buffer prefetch of
// W1/b1 one block ahead (R1's win restored), early in-iteration W2/b2 loads,
// layer-2 results paired across adjacent blocks into a row-major phi-swizzled
// out-tile (dword LDS writes; output phase reads ushort4 instead of 64x u16).

typedef unsigned short u16t;
typedef __bf16 bf16x8 __attribute__((ext_vector_type(8)));
typedef __bf16 bf16x2 __attribute__((ext_vector_type(2)));
typedef float f32x4 __attribute__((ext_vector_type(4)));

#define LDC 34     // u16 per layer-1 tile row: 32 + 2 pad (17 dwords, odd stride)
#define OT_LD 1032 // u16 per out-tile row: 1024 + 8 pad (516 dwords)

__device__ __forceinline__ u16t f2b(float f) {           // fp32 -> bf16 RNE
  union { float f; unsigned u; } v; v.f = f;
  unsigned r = v.u + 0x7FFFu + ((v.u >> 16) & 1u);
  return (u16t)(r >> 16);
}
__device__ __forceinline__ float b2f(u16t h) {
  union { unsigned u; float f; } v; v.u = ((unsigned)h) << 16;
  return v.f;
}
__device__ __forceinline__ unsigned pk2(float a, float b) {  // 2x fp32 -> packed bf16
#if __has_builtin(__builtin_amdgcn_cvt_pk_bf16_f32)
  union { bf16x2 v; unsigned u; } cv;
  cv.v = __builtin_amdgcn_cvt_pk_bf16_f32(a, b);
  return cv.u;
#else
  return (unsigned)f2b(a) | ((unsigned)f2b(b) << 16);
#endif
}

union BF { u16t us[8]; unsigned d[4]; bf16x8 v; };

// ---------------- weight pack: fp32 -> bf16 MFMA A-fragment order (transposed GEMMs) ----
// pW1[L][n][c][lane][j]  = W1[n][kz][c*16+t]    kz = L==0 ? q*8+j : 4*j+q
// pW2[L][n][kc*2+c2][lane][j] = W2[n][H][c2*16+t],  H = kc*32+(j>>2)*16+q*4+(j&3)
__global__ __launch_bounds__(256) void pack_weights(
    const float* __restrict__ W1a, const float* __restrict__ W2a,
    const float* __restrict__ W1b, const float* __restrict__ W2b,
    u16t* __restrict__ pW1, u16t* __restrict__ pW2) {
  int tidg = blockIdx.x * 256 + threadIdx.x;   // 0..32767
  int tensor = tidg >> 14;
  int r  = tidg & 16383;
  int L  = r >> 13;
  int r2 = r & 8191;
  int n    = r2 >> 8;
  int f    = (r2 >> 6) & 3;
  int lane = r2 & 63;
  int q = lane >> 4, t = lane & 15;

  union { u16t us[8]; uint4 v; } w;
  if (tensor == 0) {
    const float* src = L ? W1b : W1a;
#pragma unroll
    for (int j = 0; j < 8; j++) {
      int kz = L ? (4 * j + q) : (q * 8 + j);
      w.us[j] = f2b(src[n * 2048 + kz * 64 + f * 16 + t]);
    }
    *(uint4*)(pW1 + (size_t)((L * 32 + n) * 2048 + f * 512 + lane * 8)) = w.v;
  } else {
    const float* src = L ? W2b : W2a;
    int kc = f >> 1, c2 = f & 1;
#pragma unroll
    for (int j = 0; j < 8; j++) {
      int H = kc * 32 + (j >> 2) * 16 + q * 4 + (j & 3);
      w.us[j] = f2b(src[n * 2048 + H * 32 + c2 * 16 + t]);
    }
    *(uint4*)(pW2 + (size_t)((L * 32 + n) * 2048 + f * 512 + lane * 8)) = w.v;
  }
}

// ---------------- per-layer compute: 8 blocks per wave, all-register hidden ----------------
// w1f/bc1 arrive prologue-loaded for block w*8 (callers issue those loads early so
// they are in flight across barriers / the x-load phase).
template <int L>
__device__ __forceinline__ void compute_layer(
    const float* __restrict__ xg, const bf16x8* zfr,
    unsigned* __restrict__ tile32, unsigned* __restrict__ otile32,
    const u16t* __restrict__ pW1, const u16t* __restrict__ pW2,
    const float* __restrict__ b1, const float* __restrict__ b2,
    const bf16x8* E, int w, int q, int t,
    bf16x8 w1f[4], f32x4 bc1[4]) {
  const int lane8 = (q * 16 + t) * 8;
  float4 v0, v1;
  if (L == 0) {
    const float* gp = xg + (w * 8) * 32 + q * 8;
    v0 = *(const float4*)gp;
    v1 = *(const float4*)(gp + 4);
  }
  float stash[8];   // L==1: even-block yT values awaiting pairing
#pragma unroll
  for (int u = 0; u < 8; u++) {
    const int n = w * 8 + u;
    const int base = (L * 32 + n) * 2048 + lane8;

    // early: this block's W2 frags + b2 (consumed only after h-chain ~200cyc later)
    bf16x8 w2f[4];
#pragma unroll
    for (int c = 0; c < 4; c++) w2f[c] = *(const bf16x8*)(pW2 + base + c * 512);
    f32x4 bc2[2];
#pragma unroll
    for (int c2 = 0; c2 < 2; c2++) {
      float4 B2 = *(const float4*)(b2 + n * 32 + c2 * 16 + q * 4);
      bc2[c2] = (f32x4){B2.x, B2.y, B2.z, B2.w};
    }

    // prefetch next block's W1 frags + b1 (full iteration of slack)
    bf16x8 w1n[4];
    f32x4 bc1n[4];
    if (u < 7) {
      const int baseN = base + 2048;
#pragma unroll
      for (int c = 0; c < 4; c++) w1n[c] = *(const bf16x8*)(pW1 + baseN + c * 512);
#pragma unroll
      for (int c = 0; c < 4; c++) {
        float4 B1 = *(const float4*)(b1 + (n + 1) * 64 + c * 16 + q * 4);
        bc1n[c] = (f32x4){B1.x, B1.y, B1.z, B1.w};
      }
    }

    bf16x8 af;
    if (L == 0) {
      BF a;
      a.d[0] = pk2(v0.x, v0.y); a.d[1] = pk2(v0.z, v0.w);
      a.d[2] = pk2(v1.x, v1.y); a.d[3] = pk2(v1.z, v1.w);
      af = a.v;
      if (u < 7) {                      // next block's x loads, full iteration ahead
        const float* gp = xg + (n + 1) * 32 + q * 8;
        v0 = *(const float4*)gp;
        v1 = *(const float4*)(gp + 4);
      }
    } else {
      af = zfr[u];
    }

    // hT chunks: lane(q,t) reg r = h[c*16+q*4+r][batch t]; bias via C operand
    BF hf[2];
#pragma unroll
    for (int c = 0; c < 4; c++) {
      f32x4 acc = __builtin_amdgcn_mfma_f32_16x16x32_bf16(w1f[c], af, bc1[c], 0, 0, 0);
      float e0 = acc[0] > 0.f ? acc[0] : (__expf(acc[0]) - 1.f);
      float e1 = acc[1] > 0.f ? acc[1] : (__expf(acc[1]) - 1.f);
      float e2 = acc[2] > 0.f ? acc[2] : (__expf(acc[2]) - 1.f);
      float e3 = acc[3] > 0.f ? acc[3] : (__expf(acc[3]) - 1.f);
      hf[c >> 1].d[(c & 1) * 2 + 0] = pk2(e0, e1);
      hf[c >> 1].d[(c & 1) * 2 + 1] = pk2(e2, e3);
    }

    // yT = E@xT (+b2 in C, residual) + W2T@hT
#pragma unroll
    for (int c2 = 0; c2 < 2; c2++) {
      f32x4 acc = __builtin_amdgcn_mfma_f32_16x16x32_bf16(E[c2], af, bc2[c2], 0, 0, 0);
      acc = __builtin_amdgcn_mfma_f32_16x16x32_bf16(w2f[c2],     hf[0].v, acc, 0, 0, 0);
      acc = __builtin_amdgcn_mfma_f32_16x16x32_bf16(w2f[2 + c2], hf[1].v, acc, 0, 0, 0);
      if (L == 0) {
        // rotated 32-wide tile, paired-dword store (2-way banks, free)
        const int phys = ((c2 * 16 + q * 4) + 4 * (n >> 2)) & 31;
        const int a32 = (((n * 16 + t) * LDC) + phys) >> 1;
        tile32[a32]     = pk2(acc[0], acc[1]);
        tile32[a32 + 1] = pk2(acc[2], acc[3]);
      } else if ((u & 1) == 0) {
        // stash even block's values; paired with odd block into dword stores
#pragma unroll
        for (int r = 0; r < 4; r++) stash[c2 * 4 + r] = acc[r];
      } else {
#pragma unroll
        for (int r = 0; r < 4; r++) {
          const int cc = c2 * 16 + q * 4 + r;
          const int F  = cc * 32 + (n - 1);                       // even-n base
          const int phys = F ^ ((cc & 7) << 3) ^ (((t >> 2) & 3) << 2);
          otile32[(t * OT_LD + phys) >> 1] = pk2(stash[c2 * 4 + r], acc[r]);
        }
      }
    }
#pragma unroll
    for (int c = 0; c < 4; c++) { w1f[c] = w1n[c]; bc1[c] = bc1n[c]; }
  }
}

__global__ __launch_bounds__(256) void mixer_kernel(
    const float* __restrict__ x,
    const float* __restrict__ b1a, const float* __restrict__ b2a,
    const float* __restrict__ b1b, const float* __restrict__ b2b,
    const u16t* __restrict__ pW1, const u16t* __restrict__ pW2,
    float* __restrict__ out) {
  __shared__ union {
    unsigned t32[(32 * 16 * LDC) / 2];   // layer-1 tile, 34,816 B
    unsigned ot[(16 * OT_LD) / 2];       // layer-2 out tile, 33,024 B
  } sm;                                  // -> 4 WG/CU (grid is 4/CU anyway)
  const int tid = threadIdx.x, w = tid >> 6, lane = tid & 63;
  const int q = lane >> 4, t = lane & 15;
  const int r0 = blockIdx.x * 16;
  const float* xg = x + (size_t)(r0 + t) * 1024;
  const int lane8 = (q * 16 + t) * 8;

  // layer-1 prologue loads (block w*8) -- issued before anything else
  bf16x8 w1p[4];
  f32x4 bc1p[4];
  {
    const int base = (w * 8) * 2048 + lane8;
#pragma unroll
    for (int c = 0; c < 4; c++) w1p[c] = *(const bf16x8*)(pW1 + base + c * 512);
#pragma unroll
    for (int c = 0; c < 4; c++) {
      float4 B1 = *(const float4*)(b1a + (w * 8) * 64 + c * 16 + q * 4);
      bc1p[c] = (f32x4){B1.x, B1.y, B1.z, B1.w};
    }
  }

  // residual selector A-frags, layer 1 (k-order q*8+j)
  bf16x8 E[2];
#pragma unroll
  for (int c2 = 0; c2 < 2; c2++) {
    BF e;
#pragma unroll
    for (int j = 0; j < 8; j++)
      e.us[j] = (q * 8 + j == c2 * 16 + t) ? (u16t)0x3F80 : (u16t)0;
    E[c2] = e.v;
  }

  compute_layer<0>(xg, nullptr, sm.t32, nullptr, pW1, pW2, b1a, b2a, E, w, q, t, w1p, bc1p);
  __syncthreads();

  // layer-2 prologue loads: issue BEFORE the LDS gathers so they fly underneath
  {
    const int base = (32 + w * 8) * 2048 + lane8;
#pragma unroll
    for (int c = 0; c < 4; c++) w1p[c] = *(const bf16x8*)(pW1 + base + c * 512);
#pragma unroll
    for (int c = 0; c < 4; c++) {
      float4 B1 = *(const float4*)(b1b + (w * 8) * 64 + c * 16 + q * 4);
      bc1p[c] = (f32x4){B1.x, B1.y, B1.z, B1.w};
    }
  }

  // transition: z[t][kz=4j+q] = y1[t][kz*32+n2]; paired-dword gathers (2-way banks)
  BF zfr[8];
#pragma unroll
  for (int j = 0; j < 8; j++) {
    const int k = 4 * j + q;
    const int rb = (k * 16 + t) * LDC;
#pragma unroll
    for (int g = 0; g < 2; g++) {
      const int pg = (8 * w + 4 * g + 4 * j) & 31;   // rotated granule for block-row k
      const unsigned d0 = sm.t32[(rb + pg) >> 1];
      const unsigned d1 = sm.t32[((rb + pg) >> 1) + 1];
      zfr[4 * g + 0].us[j] = (u16t)(d0 & 0xFFFF);
      zfr[4 * g + 1].us[j] = (u16t)(d0 >> 16);
      zfr[4 * g + 2].us[j] = (u16t)(d1 & 0xFFFF);
      zfr[4 * g + 3].us[j] = (u16t)(d1 >> 16);
    }
  }

  // residual selector A-frags, layer 2 (k-order 4j+q)
#pragma unroll
  for (int c2 = 0; c2 < 2; c2++) {
    BF e;
#pragma unroll
    for (int j = 0; j < 8; j++)
      e.us[j] = (4 * j + q == c2 * 16 + t) ? (u16t)0x3F80 : (u16t)0;
    E[c2] = e.v;
  }
  __syncthreads();   // all gathers done before tile is overwritten (union!)

  compute_layer<1>(nullptr, (const bf16x8*)zfr, nullptr, sm.ot, pW1, pW2, b1b, b2b, E, w, q, t, w1p, bc1p);
  __syncthreads();

  // output: out-tile row i, F0=4*(w*64+lane); ushort4 LDS reads, float4 stores
  const u16t* ot16 = (const u16t*)sm.ot;
#pragma unroll
  for (int i = 0; i < 16; i++) {
    const int g  = w * 64 + lane;
    const int F0 = 4 * g;
    const int cc = F0 >> 5;
    const int phys = F0 ^ ((cc & 7) << 3) ^ (((i >> 2) & 3) << 2);
    ushort4 hv = *(const ushort4*)(ot16 + i * OT_LD + phys);
    float4 o;
    o.x = b2f(hv.x); o.y = b2f(hv.y); o.z = b2f(hv.z); o.w = b2f(hv.w);
    *(float4*)(out + (size_t)(r0 + i) * 1024 + F0) = o;
  }
}

extern "C" void kernel_launch(void* const* d_in, const int* in_sizes, int n_in,
                              void* d_out, int out_size, void* d_ws, size_t ws_size,
                              hipStream_t stream) {
  const float* x   = (const float*)d_in[0];
  const float* W1a = (const float*)d_in[1];
  const float* b1a = (const float*)d_in[2];
  const float* W2a = (const float*)d_in[3];
  const float* b2a = (const float*)d_in[4];
  const float* W1b = (const float*)d_in[5];
  const float* b1b = (const float*)d_in[6];
  const float* W2b = (const float*)d_in[7];
  const float* b2b = (const float*)d_in[8];
  float* out = (float*)d_out;

  u16t* pW1 = (u16t*)d_ws;
  u16t* pW2 = pW1 + 131072;   // 256 KB each, 512 KB total in d_ws

  const int rows = in_sizes[0] / 1024;

  pack_weights<<<128, 256, 0, stream>>>(W1a, W2a, W1b, W2b, pW1, pW2);
  mixer_kernel<<<rows / 16, 256, 0, stream>>>(x, b1a, b2a, b1b, b2b, pW1, pW2, out);
}

// Round 5
// 161.815 us; speedup vs baseline: 1.1153x; 1.0255x over previous
//
#include <hip/hip_runtime.h>

// BlockResMLP mixer, fused. Transposed-GEMM formulation:
//   hT = W1T @ xT          (MFMA C-layout of hT == B-operand layout of GEMM2
//                           under a hidden-dim permutation baked into the W2 pack)
//   yT = E_c2 @ xT (residual) + W2T @ hT ; biases via VALU adds (C=0 always!)
// R5 discipline (from R1-vs-R3/R4 evidence): no MFMA operand ever depends on a
// fresh load -- x preloaded into afr[8], W1 frags register-prefetched one block
// ahead, C operand is zero, biases added with v_add after the MFMA chain.
// Hidden activation never touches LDS. Transition/output phases = R3's verified
// rotated-tile scheme (17-dword odd stride -> 2-way banks, free).

typedef unsigned short u16t;
typedef __bf16 bf16x8 __attribute__((ext_vector_type(8)));
typedef __bf16 bf16x2 __attribute__((ext_vector_type(2)));
typedef float f32x4 __attribute__((ext_vector_type(4)));

#define LDC 34   // u16 per tile row: 32 cols + 2 pad (17 dwords -> odd dword stride)

__device__ __forceinline__ u16t f2b(float f) {           // fp32 -> bf16 RNE
  union { float f; unsigned u; } v; v.f = f;
  unsigned r = v.u + 0x7FFFu + ((v.u >> 16) & 1u);
  return (u16t)(r >> 16);
}
__device__ __forceinline__ float b2f(u16t h) {
  union { unsigned u; float f; } v; v.u = ((unsigned)h) << 16;
  return v.f;
}
__device__ __forceinline__ unsigned pk2(float a, float b) {  // 2x fp32 -> packed bf16
#if __has_builtin(__builtin_amdgcn_cvt_pk_bf16_f32)
  union { bf16x2 v; unsigned u; } cv;
  cv.v = __builtin_amdgcn_cvt_pk_bf16_f32(a, b);
  return cv.u;
#else
  return (unsigned)f2b(a) | ((unsigned)f2b(b) << 16);
#endif
}

union BF { u16t us[8]; unsigned d[4]; bf16x8 v; };

// ---------------- weight pack: fp32 -> bf16 MFMA A-fragment order (transposed GEMMs) ----
// pW1[L][n][c][lane][j]  = W1[n][kz][c*16+t]    kz = L==0 ? q*8+j : 4*j+q
// pW2[L][n][kc*2+c2][lane][j] = W2[n][H][c2*16+t],  H = kc*32+(j>>2)*16+q*4+(j&3)
__global__ __launch_bounds__(256) void pack_weights(
    const float* __restrict__ W1a, const float* __restrict__ W2a,
    const float* __restrict__ W1b, const float* __restrict__ W2b,
    u16t* __restrict__ pW1, u16t* __restrict__ pW2) {
  int tidg = blockIdx.x * 256 + threadIdx.x;   // 0..32767
  int tensor = tidg >> 14;
  int r  = tidg & 16383;
  int L  = r >> 13;
  int r2 = r & 8191;
  int n    = r2 >> 8;
  int f    = (r2 >> 6) & 3;
  int lane = r2 & 63;
  int q = lane >> 4, t = lane & 15;

  union { u16t us[8]; uint4 v; } w;
  if (tensor == 0) {
    const float* src = L ? W1b : W1a;
#pragma unroll
    for (int j = 0; j < 8; j++) {
      int kz = L ? (4 * j + q) : (q * 8 + j);
      w.us[j] = f2b(src[n * 2048 + kz * 64 + f * 16 + t]);
    }
    *(uint4*)(pW1 + (size_t)((L * 32 + n) * 2048 + f * 512 + lane * 8)) = w.v;
  } else {
    const float* src = L ? W2b : W2a;
    int kc = f >> 1, c2 = f & 1;
#pragma unroll
    for (int j = 0; j < 8; j++) {
      int H = kc * 32 + (j >> 2) * 16 + q * 4 + (j & 3);
      w.us[j] = f2b(src[n * 2048 + H * 32 + c2 * 16 + t]);
    }
    *(uint4*)(pW2 + (size_t)((L * 32 + n) * 2048 + f * 512 + lane * 8)) = w.v;
  }
}

// ---------------- per-layer compute: 8 blocks per wave, all-register hidden ----------------
// afr: 8 preloaded A-operand (batch) fragments. w1f: W1 frags for block w*8,
// prologue-loaded by the caller (so they fly under earlier work). C=0 MFMAs;
// biases applied as VALU adds from iter-top float4 loads.
template <int L>
__device__ __forceinline__ void compute_layer(
    const bf16x8* afr, unsigned* __restrict__ tile32,
    const u16t* __restrict__ pW1, const u16t* __restrict__ pW2,
    const float* __restrict__ b1, const float* __restrict__ b2,
    const bf16x8* E, int w, int q, int t,
    bf16x8 w1f[4]) {
  const f32x4 zf = {0.f, 0.f, 0.f, 0.f};
  const int lane8 = (q * 16 + t) * 8;
#pragma unroll
  for (int u = 0; u < 8; u++) {
    const int n = w * 8 + u;
    const int base = (L * 32 + n) * 2048 + lane8;

    // iter-top loads: this block's W2 frags + biases (consumed after slack)
    bf16x8 w2f[4];
#pragma unroll
    for (int c = 0; c < 4; c++) w2f[c] = *(const bf16x8*)(pW2 + base + c * 512);
    float4 b1v[4];
#pragma unroll
    for (int c = 0; c < 4; c++) b1v[c] = *(const float4*)(b1 + n * 64 + c * 16 + q * 4);
    float4 b2v0 = *(const float4*)(b2 + n * 32 + q * 4);
    float4 b2v1 = *(const float4*)(b2 + n * 32 + 16 + q * 4);

    // prefetch next block's W1 frags (full iteration of slack)
    bf16x8 w1n[4];
    if (u < 7) {
#pragma unroll
      for (int c = 0; c < 4; c++) w1n[c] = *(const bf16x8*)(pW1 + base + 2048 + c * 512);
    }

    // GEMM1: hT chunks, C=0; bias+ELU via VALU; in-lane relabel to GEMM2 B-frags
    BF hf[2];
#pragma unroll
    for (int c = 0; c < 4; c++) {
      f32x4 acc = __builtin_amdgcn_mfma_f32_16x16x32_bf16(w1f[c], afr[u], zf, 0, 0, 0);
      float e0 = acc[0] + b1v[c].x; e0 = e0 > 0.f ? e0 : (__expf(e0) - 1.f);
      float e1 = acc[1] + b1v[c].y; e1 = e1 > 0.f ? e1 : (__expf(e1) - 1.f);
      float e2 = acc[2] + b1v[c].z; e2 = e2 > 0.f ? e2 : (__expf(e2) - 1.f);
      float e3 = acc[3] + b1v[c].w; e3 = e3 > 0.f ? e3 : (__expf(e3) - 1.f);
      hf[c >> 1].d[(c & 1) * 2 + 0] = pk2(e0, e1);
      hf[c >> 1].d[(c & 1) * 2 + 1] = pk2(e2, e3);
    }

    // GEMM2 + residual selector, C=0; bias added before pack; rotated tile write
#pragma unroll
    for (int c2 = 0; c2 < 2; c2++) {
      f32x4 acc = __builtin_amdgcn_mfma_f32_16x16x32_bf16(E[c2], afr[u], zf, 0, 0, 0);
      acc = __builtin_amdgcn_mfma_f32_16x16x32_bf16(w2f[c2],     hf[0].v, acc, 0, 0, 0);
      acc = __builtin_amdgcn_mfma_f32_16x16x32_bf16(w2f[2 + c2], hf[1].v, acc, 0, 0, 0);
      float4 bb = c2 ? b2v1 : b2v0;
      const int phys = ((c2 * 16 + q * 4) + 4 * (n >> 2)) & 31;   // rotation by block row
      const int a32 = (((n * 16 + t) * LDC) + phys) >> 1;         // even u16 -> dword idx
      tile32[a32]     = pk2(acc[0] + bb.x, acc[1] + bb.y);
      tile32[a32 + 1] = pk2(acc[2] + bb.z, acc[3] + bb.w);
    }
#pragma unroll
    for (int c = 0; c < 4; c++) w1f[c] = w1n[c];
  }
}

__global__ __launch_bounds__(256) void mixer_kernel(
    const float* __restrict__ x,
    const float* __restrict__ b1a, const float* __restrict__ b2a,
    const float* __restrict__ b1b, const float* __restrict__ b2b,
    const u16t* __restrict__ pW1, const u16t* __restrict__ pW2,
    float* __restrict__ out) {
  __shared__ unsigned tile32[(32 * 16 * LDC) / 2];   // 34,816 B -> 4 WG/CU
  const u16t* tile16 = (const u16t*)tile32;
  const int tid = threadIdx.x, w = tid >> 6, lane = tid & 63;
  const int q = lane >> 4, t = lane & 15;
  const int r0 = blockIdx.x * 16;
  const int lane8 = (q * 16 + t) * 8;

  // ---- x preload into afr[8] (HBM loads issued first; resident thereafter) ----
  const float* xg = x + (size_t)(r0 + t) * 1024;
  bf16x8 afr[8];
#pragma unroll
  for (int u = 0; u < 8; u++) {
    const float* gp = xg + (w * 8 + u) * 32 + q * 8;
    float4 v0 = *(const float4*)gp;
    float4 v1 = *(const float4*)(gp + 4);
    BF a;
    a.d[0] = pk2(v0.x, v0.y); a.d[1] = pk2(v0.z, v0.w);
    a.d[2] = pk2(v1.x, v1.y); a.d[3] = pk2(v1.z, v1.w);
    afr[u] = a.v;
  }

  // layer-1 prologue: W1 frags for block w*8
  bf16x8 w1p[4];
#pragma unroll
  for (int c = 0; c < 4; c++)
    w1p[c] = *(const bf16x8*)(pW1 + (w * 8) * 2048 + c * 512 + lane8);

  // residual selector A-frags, layer 1 (k-order q*8+j)
  bf16x8 E[2];
#pragma unroll
  for (int c2 = 0; c2 < 2; c2++) {
    BF e;
#pragma unroll
    for (int j = 0; j < 8; j++)
      e.us[j] = (q * 8 + j == c2 * 16 + t) ? (u16t)0x3F80 : (u16t)0;
    E[c2] = e.v;
  }

  compute_layer<0>(afr, tile32, pW1, pW2, b1a, b2a, E, w, q, t, w1p);
  __syncthreads();

  // layer-2 prologue W1 loads: issue BEFORE the LDS gathers so they fly underneath
#pragma unroll
  for (int c = 0; c < 4; c++)
    w1p[c] = *(const bf16x8*)(pW1 + (32 + w * 8) * 2048 + c * 512 + lane8);

  // transition: z[t][kz=4j+q] = y1[t][kz*32+n2]; paired-dword gathers (2-way banks)
  BF zfr[8];
#pragma unroll
  for (int j = 0; j < 8; j++) {
    const int k = 4 * j + q;
    const int rb = (k * 16 + t) * LDC;
#pragma unroll
    for (int g = 0; g < 2; g++) {
      const int pg = (8 * w + 4 * g + 4 * j) & 31;   // rotated granule for block-row k
      const unsigned d0 = tile32[(rb + pg) >> 1];
      const unsigned d1 = tile32[((rb + pg) >> 1) + 1];
      zfr[4 * g + 0].us[j] = (u16t)(d0 & 0xFFFF);
      zfr[4 * g + 1].us[j] = (u16t)(d0 >> 16);
      zfr[4 * g + 2].us[j] = (u16t)(d1 & 0xFFFF);
      zfr[4 * g + 3].us[j] = (u16t)(d1 >> 16);
    }
  }

  // residual selector A-frags, layer 2 (k-order 4j+q)
#pragma unroll
  for (int c2 = 0; c2 < 2; c2++) {
    BF e;
#pragma unroll
    for (int j = 0; j < 8; j++)
      e.us[j] = (4 * j + q == c2 * 16 + t) ? (u16t)0x3F80 : (u16t)0;
    E[c2] = e.v;
  }
  __syncthreads();   // all gathers done before tile is overwritten

  compute_layer<1>((const bf16x8*)zfr, tile32, pW1, pW2, b1b, b2b, E, w, q, t, w1p);
  __syncthreads();

  // output: tile[n2][row][phys(cc)] -> out[row][F=cc*32+n2], coalesced float4 stores
  const int row = lane & 15, l4 = lane >> 4;
#pragma unroll
  for (int i = 0; i < 16; i++) {
    const int F0 = 4 * (i * 16 + w * 4 + l4);
    const int bn = F0 & 31, cc = F0 >> 5;
    const int phys = (cc + 4 * (bn >> 2)) & 31;
    union { float4 v; float f[4]; } o;
#pragma unroll
    for (int e = 0; e < 4; e++)
      o.f[e] = b2f(tile16[((bn + e) * 16 + row) * LDC + phys]);
    *(float4*)(out + (size_t)(r0 + row) * 1024 + F0) = o.v;
  }
}

extern "C" void kernel_launch(void* const* d_in, const int* in_sizes, int n_in,
                              void* d_out, int out_size, void* d_ws, size_t ws_size,
                              hipStream_t stream) {
  const float* x   = (const float*)d_in[0];
  const float* W1a = (const float*)d_in[1];
  const float* b1a = (const float*)d_in[2];
  const float* W2a = (const float*)d_in[3];
  const float* b2a = (const float*)d_in[4];
  const float* W1b = (const float*)d_in[5];
  const float* b1b = (const float*)d_in[6];
  const float* W2b = (const float*)d_in[7];
  const float* b2b = (const float*)d_in[8];
  float* out = (float*)d_out;

  u16t* pW1 = (u16t*)d_ws;
  u16t* pW2 = pW1 + 131072;   // 256 KB each, 512 KB total in d_ws

  const int rows = in_sizes[0] / 1024;

  pack_weights<<<128, 256, 0, stream>>>(W1a, W2a, W1b, W2b, pW1, pW2);
  mixer_kernel<<<rows / 16, 256, 0, stream>>>(x, b1a, b2a, b1b, b2b, pW1, pW2, out);
}